// Round 14
// baseline (502.050 us; speedup 1.0000x reference)
//
#include <hip/hip_runtime.h>
#include <hip/hip_cooperative_groups.h>
namespace cg = cooperative_groups;

#define CDIM 128
#define NGRAPH 256
#define BSH 7                 // 128 nodes per bucket
#define BCAP 4096             // LDS sort capacity (mean 2048, +45 sigma)
#define NBLK 256              // blocks for the cooperative prep kernel

typedef unsigned short bf16_t;
typedef __attribute__((ext_vector_type(8))) short bf16x8;  // MFMA A/B frag (4 VGPRs)
typedef __attribute__((ext_vector_type(4))) float f32x4;   // MFMA C/D frag

__device__ __forceinline__ float bflo(unsigned u) { return __uint_as_float(u << 16); }
__device__ __forceinline__ float bfhi(unsigned u) { return __uint_as_float(u & 0xffff0000u); }
__device__ __forceinline__ unsigned short f2bf(float f) {
  unsigned u = __float_as_uint(f);
  u += 0x7fffu + ((u >> 16) & 1u);   // round-to-nearest-even
  return (unsigned short)(u >> 16);
}

// ================= cooperative preprocessing mega-kernel =====================
// One launch replaces: memset(gb) + wprep + phist + bscan + boff + pscatter +
// csort2. 256 blocks x 1024 threads, grid.sync() between phases. All phase
// bodies are the R12-proven algorithms.
__global__ __launch_bounds__(1024) void k_prep(
    const float* __restrict__ W1, const float* __restrict__ W2,
    bf16_t* __restrict__ Wtg1, bf16_t* __restrict__ Wtg2,
    const int* __restrict__ src, const int* __restrict__ dst,
    int* __restrict__ phist, int* __restrict__ btot, int* __restrict__ bbase,
    unsigned* __restrict__ tmp, int* __restrict__ rowptr,
    float* __restrict__ dinv, int* __restrict__ col,
    float* __restrict__ gb, int E, int N, int NB) {
  cg::grid_group grid = cg::this_grid();
  __shared__ int hist[1024];        // phist hist / boff scan buf / pscatter cur
  __shared__ int wsum2[4][4];       // bscan subgroup partials
  __shared__ int shist[128];        // csort per-bucket
  __shared__ int ssc[128];
  __shared__ int lcur[128];
  __shared__ unsigned buf[BCAP];
  int blk = blockIdx.x, tid = threadIdx.x;
  int gidx = blk * 1024 + tid;

  // ---- phase 0: W transpose->bf16, zero gb ----
  if (gidx < 16384) {
    int n = gidx >> 7, k = gidx & 127;
    Wtg1[n * 128 + k] = f2bf(W1[k * 128 + n]);
    Wtg2[n * 128 + k] = f2bf(W2[k * 128 + n]);
  }
  if (gidx < NGRAPH * CDIM) gb[gidx] = 0.f;

  // ---- phase 1: per-block LDS histogram over buckets ----
  for (int i = tid; i < NB; i += 1024) hist[i] = 0;
  __syncthreads();
  int tile = (E + NBLK - 1) / NBLK;
  int lo = blk * tile;
  int hi = lo + tile; if (hi > E) hi = E;
  for (int i = lo + tid; i < hi; i += 1024) atomicAdd(&hist[dst[i] >> BSH], 1);
  __syncthreads();
  for (int i = tid; i < NB; i += 1024) phist[i * NBLK + blk] = hist[i];
  grid.sync();

  // ---- phase 2: per-bucket scan of phist rows (4 buckets/block) ----
  {
    int sub = tid >> 8;            // 0..3 subgroup of 256 threads
    int stid = tid & 255;
    int slane = stid & 63, swave = stid >> 6;
    int b2 = blk + 256 * sub;      // covers 0..1023 >= NB
    int orig = (b2 < NB) ? phist[b2 * NBLK + stid] : 0;
    int v = orig;
#pragma unroll
    for (int ofs = 1; ofs < 64; ofs <<= 1) {
      int u = __shfl_up(v, ofs, 64);
      if (slane >= ofs) v += u;
    }
    if (slane == 63) wsum2[sub][swave] = v;
    __syncthreads();
    int add = 0;
#pragma unroll
    for (int w = 0; w < 3; w++) if (w < swave) add += wsum2[sub][w];
    int incl = v + add;
    if (b2 < NB) {
      phist[b2 * NBLK + stid] = incl - orig;   // within-bucket exclusive
      if (stid == 255) btot[b2] = incl;
    }
  }
  grid.sync();

  // ---- phase 3: exclusive scan of bucket totals (block 0) ----
  if (blk == 0) {
    int v = (tid < NB) ? btot[tid] : 0;
    hist[tid] = v;
    __syncthreads();
    for (int ofs = 1; ofs < 1024; ofs <<= 1) {
      int u = (tid >= ofs) ? hist[tid - ofs] : 0;
      __syncthreads();
      hist[tid] += u;
      __syncthreads();
    }
    if (tid < NB) bbase[tid] = hist[tid] - v;
    if (tid == NB) bbase[NB] = hist[NB - 1];
  }
  grid.sync();

  // ---- phase 4: exact-offset scatter (zero global atomics) ----
  for (int i = tid; i < NB; i += 1024) hist[i] = bbase[i] + phist[i * NBLK + blk];
  __syncthreads();
  for (int i = lo + tid; i < hi; i += 1024) {
    int d = dst[i];
    int p = atomicAdd(&hist[d >> BSH], 1);
    tmp[p] = (unsigned)src[i] | ((unsigned)(d & 127) << 20);
  }
  grid.sync();

  // ---- phase 5: per-bucket counting sort; emits rowptr/dinv/col ----
  if (blk == 0 && tid == 0) rowptr[N] = E;
  for (int b = blk; b < NB; b += NBLK) {
    __syncthreads();
    int n0 = b << BSH;
    int base = bbase[b];
    int cnt = bbase[b + 1] - base;
    if (tid < 128) shist[tid] = 0;
    __syncthreads();
    for (int i = tid; i < cnt; i += 1024) atomicAdd(&shist[(tmp[base + i] >> 20) & 127], 1);
    __syncthreads();
    if (tid < 128) ssc[tid] = shist[tid];
    __syncthreads();
    for (int ofs = 1; ofs < 128; ofs <<= 1) {
      int v = (tid < 128 && tid >= ofs) ? ssc[tid - ofs] : 0;
      __syncthreads();
      if (tid < 128) ssc[tid] += v;
      __syncthreads();
    }
    if (tid < 128) {
      int excl = ssc[tid] - shist[tid];
      lcur[tid] = excl;
      int node = n0 + tid;
      if (node < N) {
        rowptr[node] = base + excl;
        dinv[node] = rsqrtf((float)shist[tid] + 1.0f);
      }
    }
    __syncthreads();
    if (cnt <= BCAP) {
      for (int i = tid; i < cnt; i += 1024) {
        unsigned pk = tmp[base + i];
        int p = atomicAdd(&lcur[(pk >> 20) & 127], 1);
        buf[p] = pk & 0xFFFFFu;
      }
      __syncthreads();
      for (int i = tid; i < cnt; i += 1024) col[base + i] = (int)buf[i];
    } else {
      for (int i = tid; i < cnt; i += 1024) {
        unsigned pk = tmp[base + i];
        int p = atomicAdd(&lcur[(pk >> 20) & 127], 1);
        col[base + p] = (int)(pk & 0xFFFFFu);
      }
    }
  }
}

// ---------- MFMA GEMM: [M x 128] @ [128 x 128], bf16 MFMA, fp32 acc, bf16 out ----
#define WSTRIDE 136
template <int BF16IN>
__global__ __launch_bounds__(256) void k_gemm(const void* __restrict__ Ap,
    const bf16_t* __restrict__ Wtg, bf16_t* __restrict__ Co, int M) {
  __shared__ bf16_t Wt[128 * WSTRIDE];
  int tid = threadIdx.x;
  for (int c2 = tid; c2 < 2048; c2 += 256) {   // 2048 x 8-bf16 chunks
    int n = c2 >> 4;
    int k8 = (c2 & 15) << 3;
    *(uint4*)&Wt[n * WSTRIDE + k8] = *(const uint4*)&Wtg[n * 128 + k8];
  }
  __syncthreads();

  int wave = tid >> 6;
  int lane = tid & 63;
  int m = lane & 15;
  int q = lane >> 4;
  int nstrips = (M + 63) >> 6;

  for (int s = blockIdx.x; s < nstrips; s += gridDim.x) {
    int rowA = s * 64 + wave * 16 + m;
    if (rowA > M - 1) rowA = M - 1;
    bf16x8 a[4];
#pragma unroll
    for (int c = 0; c < 4; c++) {
      if (BF16IN) {
        a[c] = *(const bf16x8*)((const bf16_t*)Ap + (size_t)rowA * CDIM + c * 32 + q * 8);
      } else {
        const float* ap = (const float*)Ap + (size_t)rowA * CDIM + c * 32 + q * 8;
        float4 f0 = *(const float4*)ap;
        float4 f1 = *(const float4*)(ap + 4);
        union { bf16x8 v; unsigned short u[8]; } ua;
        ua.u[0] = f2bf(f0.x); ua.u[1] = f2bf(f0.y); ua.u[2] = f2bf(f0.z); ua.u[3] = f2bf(f0.w);
        ua.u[4] = f2bf(f1.x); ua.u[5] = f2bf(f1.y); ua.u[6] = f2bf(f1.z); ua.u[7] = f2bf(f1.w);
        a[c] = ua.v;
      }
    }
#pragma unroll
    for (int t = 0; t < 8; t++) {
      f32x4 acc = {0.f, 0.f, 0.f, 0.f};
#pragma unroll
      for (int c = 0; c < 4; c++) {
        bf16x8 bv = *(const bf16x8*)&Wt[(t * 16 + m) * WSTRIDE + c * 32 + q * 8];
        acc = __builtin_amdgcn_mfma_f32_16x16x32_bf16(a[c], bv, acc, 0, 0, 0);
      }
#pragma unroll
      for (int r = 0; r < 4; r++) {
        int row = s * 64 + wave * 16 + q * 4 + r;
        if (row < M) Co[(size_t)row * CDIM + t * 16 + m] = f2bf(acc[r]);
      }
    }
  }
}

// ---------- layer-1 gather aggregation (R9 structure: VGPR 24) ----------------
__global__ __launch_bounds__(256) void k_agg0(const bf16_t* __restrict__ t,
    const int* __restrict__ rowptr, const int* __restrict__ col,
    const float* __restrict__ dinv, const float* __restrict__ bias,
    bf16_t* __restrict__ out, int N) {
  int wave = threadIdx.x >> 6;
  int lane = threadIdx.x & 63;
  int node = blockIdx.x * 4 + wave;
  if (node >= N) return;
  int half = lane >> 5;
  int c = lane & 31;
  const uint2* tp = (const uint2*)t;
  float di = dinv[node];
  uint2 sv = tp[(size_t)node * 32 + c];
  float sw = (half == 0) ? di : 0.f;
  float a0 = bflo(sv.x) * sw, a1 = bfhi(sv.x) * sw;
  float a2 = bflo(sv.y) * sw, a3 = bfhi(sv.y) * sw;
  int beg = rowptr[node], end = rowptr[node + 1];
  for (int base = beg; base < end; base += 64) {
    int rem = end - base;
    int cnt = rem < 64 ? rem : 64;
    int sL = 0; float wL = 0.f;
    if (lane < cnt) { sL = col[base + lane]; wL = dinv[sL]; }
    for (int k = 0; k < cnt; k += 8) {
      int j0 = k + half, j1 = k + 2 + half, j2 = k + 4 + half, j3 = k + 6 + half;
      int s0 = __shfl(sL, j0, 64); float w0 = __shfl(wL, j0, 64);
      int s1 = __shfl(sL, j1, 64); float w1 = __shfl(wL, j1, 64);
      int s2 = __shfl(sL, j2, 64); float w2 = __shfl(wL, j2, 64);
      int s3 = __shfl(sL, j3, 64); float w3 = __shfl(wL, j3, 64);
      if (j0 >= cnt) { s0 = node; w0 = 0.f; }
      if (j1 >= cnt) { s1 = node; w1 = 0.f; }
      if (j2 >= cnt) { s2 = node; w2 = 0.f; }
      if (j3 >= cnt) { s3 = node; w3 = 0.f; }
      uint2 v0 = tp[(size_t)s0 * 32 + c];
      uint2 v1 = tp[(size_t)s1 * 32 + c];
      uint2 v2 = tp[(size_t)s2 * 32 + c];
      uint2 v3 = tp[(size_t)s3 * 32 + c];
      a0 = fmaf(bflo(v0.x), w0, a0); a1 = fmaf(bfhi(v0.x), w0, a1);
      a2 = fmaf(bflo(v0.y), w0, a2); a3 = fmaf(bfhi(v0.y), w0, a3);
      a0 = fmaf(bflo(v1.x), w1, a0); a1 = fmaf(bfhi(v1.x), w1, a1);
      a2 = fmaf(bflo(v1.y), w1, a2); a3 = fmaf(bfhi(v1.y), w1, a3);
      a0 = fmaf(bflo(v2.x), w2, a0); a1 = fmaf(bfhi(v2.x), w2, a1);
      a2 = fmaf(bflo(v2.y), w2, a2); a3 = fmaf(bfhi(v2.y), w2, a3);
      a0 = fmaf(bflo(v3.x), w3, a0); a1 = fmaf(bfhi(v3.x), w3, a1);
      a2 = fmaf(bflo(v3.y), w3, a2); a3 = fmaf(bfhi(v3.y), w3, a3);
    }
  }
  a0 += __shfl_xor(a0, 32, 64);
  a1 += __shfl_xor(a1, 32, 64);
  a2 += __shfl_xor(a2, 32, 64);
  a3 += __shfl_xor(a3, 32, 64);
  if (half == 0) {
    float4 bb = ((const float4*)bias)[c];
    float o0 = fmaxf(fmaf(di, a0, bb.x), 0.f);
    float o1 = fmaxf(fmaf(di, a1, bb.y), 0.f);
    float o2 = fmaxf(fmaf(di, a2, bb.z), 0.f);
    float o3 = fmaxf(fmaf(di, a3, bb.w), 0.f);
    uint2 o;
    o.x = ((unsigned)f2bf(o1) << 16) | f2bf(o0);
    o.y = ((unsigned)f2bf(o3) << 16) | f2bf(o2);
    ((uint2*)(out + (size_t)node * CDIM))[c] = o;
  }
}

// ---------- layer-2 gather aggregation fused with mean-pool -------------------
// 8 consecutive nodes per wave (16 was wave-starved: 6250 waves < 8192 slots,
// occ 51% — R13). Pooled sums in registers; atomic flush on graph change.
__global__ __launch_bounds__(256) void k_aggp(const bf16_t* __restrict__ t,
    const int* __restrict__ rowptr, const int* __restrict__ col,
    const float* __restrict__ dinv, const float* __restrict__ bias,
    const int* __restrict__ batch, float* __restrict__ gsum, int N) {
  int wave = threadIdx.x >> 6;
  int lane = threadIdx.x & 63;
  int half = lane >> 5;
  int c = lane & 31;
  const uint2* tp = (const uint2*)t;
  float4 bb = ((const float4*)bias)[c];
  int n0 = (blockIdx.x * 4 + wave) * 8;
  if (n0 >= N) return;
  int nEnd = n0 + 8; if (nEnd > N) nEnd = N;
  float p0 = 0.f, p1 = 0.f, p2 = 0.f, p3 = 0.f;
  int curb = batch[n0];

  for (int node = n0; node < nEnd; node++) {
    float di = dinv[node];
    uint2 sv = tp[(size_t)node * 32 + c];
    float sw = (half == 0) ? di : 0.f;
    float a0 = bflo(sv.x) * sw, a1 = bfhi(sv.x) * sw;
    float a2 = bflo(sv.y) * sw, a3 = bfhi(sv.y) * sw;
    int beg = rowptr[node], end = rowptr[node + 1];
    for (int base = beg; base < end; base += 64) {
      int rem = end - base;
      int cnt = rem < 64 ? rem : 64;
      int sL = 0; float wL = 0.f;
      if (lane < cnt) { sL = col[base + lane]; wL = dinv[sL]; }
      for (int k = 0; k < cnt; k += 8) {
        int j0 = k + half, j1 = k + 2 + half, j2 = k + 4 + half, j3 = k + 6 + half;
        int s0 = __shfl(sL, j0, 64); float w0 = __shfl(wL, j0, 64);
        int s1 = __shfl(sL, j1, 64); float w1 = __shfl(wL, j1, 64);
        int s2 = __shfl(sL, j2, 64); float w2 = __shfl(wL, j2, 64);
        int s3 = __shfl(sL, j3, 64); float w3 = __shfl(wL, j3, 64);
        if (j0 >= cnt) { s0 = node; w0 = 0.f; }
        if (j1 >= cnt) { s1 = node; w1 = 0.f; }
        if (j2 >= cnt) { s2 = node; w2 = 0.f; }
        if (j3 >= cnt) { s3 = node; w3 = 0.f; }
        uint2 v0 = tp[(size_t)s0 * 32 + c];
        uint2 v1 = tp[(size_t)s1 * 32 + c];
        uint2 v2 = tp[(size_t)s2 * 32 + c];
        uint2 v3 = tp[(size_t)s3 * 32 + c];
        a0 = fmaf(bflo(v0.x), w0, a0); a1 = fmaf(bfhi(v0.x), w0, a1);
        a2 = fmaf(bflo(v0.y), w0, a2); a3 = fmaf(bfhi(v0.y), w0, a3);
        a0 = fmaf(bflo(v1.x), w1, a0); a1 = fmaf(bfhi(v1.x), w1, a1);
        a2 = fmaf(bflo(v1.y), w1, a2); a3 = fmaf(bfhi(v1.y), w1, a3);
        a0 = fmaf(bflo(v2.x), w2, a0); a1 = fmaf(bfhi(v2.x), w2, a1);
        a2 = fmaf(bflo(v2.y), w2, a2); a3 = fmaf(bfhi(v2.y), w2, a3);
        a0 = fmaf(bflo(v3.x), w3, a0); a1 = fmaf(bfhi(v3.x), w3, a1);
        a2 = fmaf(bflo(v3.y), w3, a2); a3 = fmaf(bfhi(v3.y), w3, a3);
      }
    }
    a0 += __shfl_xor(a0, 32, 64);
    a1 += __shfl_xor(a1, 32, 64);
    a2 += __shfl_xor(a2, 32, 64);
    a3 += __shfl_xor(a3, 32, 64);
    if (half == 0) {
      float o0 = fmaxf(fmaf(di, a0, bb.x), 0.f);
      float o1 = fmaxf(fmaf(di, a1, bb.y), 0.f);
      float o2 = fmaxf(fmaf(di, a2, bb.z), 0.f);
      float o3 = fmaxf(fmaf(di, a3, bb.w), 0.f);
      int b = batch[node];
      if (b != curb) {
        atomicAdd(&gsum[curb * CDIM + c * 4 + 0], p0);
        atomicAdd(&gsum[curb * CDIM + c * 4 + 1], p1);
        atomicAdd(&gsum[curb * CDIM + c * 4 + 2], p2);
        atomicAdd(&gsum[curb * CDIM + c * 4 + 3], p3);
        curb = b; p0 = p1 = p2 = p3 = 0.f;
      }
      p0 += __uint_as_float((unsigned)f2bf(o0) << 16);
      p1 += __uint_as_float((unsigned)f2bf(o1) << 16);
      p2 += __uint_as_float((unsigned)f2bf(o2) << 16);
      p3 += __uint_as_float((unsigned)f2bf(o3) << 16);
    }
  }
  if (half == 0) {
    atomicAdd(&gsum[curb * CDIM + c * 4 + 0], p0);
    atomicAdd(&gsum[curb * CDIM + c * 4 + 1], p1);
    atomicAdd(&gsum[curb * CDIM + c * 4 + 2], p2);
    atomicAdd(&gsum[curb * CDIM + c * 4 + 3], p3);
  }
}

// ---------- fused MLP head: pool-divide + mlp1 + mlp2 + mlp3 ------------------
__global__ __launch_bounds__(512) void k_mlp(const float* __restrict__ g,
    const int* __restrict__ batch, int N,
    const float* __restrict__ Wm1, const float* __restrict__ bm1,
    const float* __restrict__ Wm2, const float* __restrict__ bm2,
    const float* __restrict__ wm3, const float* __restrict__ bm3,
    float* __restrict__ out) {
  __shared__ float gs[CDIM];
  __shared__ float m1s[500];
  __shared__ float m2s[100];
  int bi = blockIdx.x, tid = threadIdx.x;
  if (tid < CDIM) {
    int lo = 0, hi = N;
    while (lo < hi) { int mid = (lo + hi) >> 1; if (batch[mid] < bi) lo = mid + 1; else hi = mid; }
    int s = lo;
    lo = 0; hi = N;
    int key = bi + 1;
    while (lo < hi) { int mid = (lo + hi) >> 1; if (batch[mid] < key) lo = mid + 1; else hi = mid; }
    float inv = 1.f / fmaxf((float)(lo - s), 1.f);
    gs[tid] = g[bi * CDIM + tid] * inv;
  }
  __syncthreads();
  if (tid < 500) {
    float acc = bm1[tid];
#pragma unroll 4
    for (int k = 0; k < CDIM; k++) acc = fmaf(gs[k], Wm1[k * 500 + tid], acc);
    m1s[tid] = fmaxf(acc, 0.f);
  }
  __syncthreads();
  if (tid < 100) {
    float acc = bm2[tid];
    for (int k = 0; k < 500; k++) acc = fmaf(m1s[k], Wm2[k * 100 + tid], acc);
    m2s[tid] = fmaxf(acc, 0.f) * wm3[tid];
  }
  __syncthreads();
  if (tid < 64) {
    float v = m2s[tid] + ((tid + 64 < 100) ? m2s[tid + 64] : 0.f);
#pragma unroll
    for (int ofs = 32; ofs > 0; ofs >>= 1) v += __shfl_down(v, ofs, 64);
    if (tid == 0) out[bi] = v + bm3[0];
  }
}

static inline size_t align_up(size_t v) { return (v + 255) & ~(size_t)255; }

extern "C" void kernel_launch(void* const* d_in, const int* in_sizes, int n_in,
                              void* d_out, int out_size, void* d_ws, size_t ws_size,
                              hipStream_t stream) {
  const float* x   = (const float*)d_in[0];
  const int*   ei  = (const int*)d_in[1];
  const int*   bat = (const int*)d_in[2];
  const float* W1  = (const float*)d_in[3];
  const float* b1  = (const float*)d_in[4];
  const float* W2  = (const float*)d_in[5];
  const float* b2  = (const float*)d_in[6];
  const float* Wm1 = (const float*)d_in[7];
  const float* bm1 = (const float*)d_in[8];
  const float* Wm2 = (const float*)d_in[9];
  const float* bm2 = (const float*)d_in[10];
  const float* Wm3 = (const float*)d_in[11];
  const float* bm3 = (const float*)d_in[12];
  float* out = (float*)d_out;

  int E = in_sizes[1] / 2;
  int N = in_sizes[2];
  const int* src = ei;
  const int* dst = ei + E;
  int NB = (N + 127) >> BSH;
  const int M  = NB * NBLK;              // phist elements

  char* p = (char*)d_ws;
  bf16_t* t    = (bf16_t*)p;   p += align_up((size_t)N * CDIM * 2);
  bf16_t* h    = (bf16_t*)p;   p += align_up((size_t)N * CDIM * 2);
  int* rowptr  = (int*)p;      p += align_up((size_t)(N + 1) * 4);
  int* colx    = (int*)p;      p += align_up((size_t)E * 4);
  unsigned* tmp= (unsigned*)p; p += align_up((size_t)E * 4);
  float* dinv  = (float*)p;    p += align_up((size_t)N * 4);
  int* phist   = (int*)p;      p += align_up((size_t)M * 4);
  int* btot    = (int*)p;      p += align_up((size_t)NB * 4);
  int* bbase   = (int*)p;      p += align_up((size_t)(NB + 1) * 4);
  bf16_t* Wtg1 = (bf16_t*)p;   p += align_up((size_t)CDIM * CDIM * 2);
  bf16_t* Wtg2 = (bf16_t*)p;   p += align_up((size_t)CDIM * CDIM * 2);
  float* gb    = (float*)p;    p += align_up((size_t)NGRAPH * CDIM * 4);
  (void)ws_size; (void)n_in; (void)out_size;

  void* kargs[] = {(void*)&W1, (void*)&W2, (void*)&Wtg1, (void*)&Wtg2,
                   (void*)&src, (void*)&dst, (void*)&phist, (void*)&btot,
                   (void*)&bbase, (void*)&tmp, (void*)&rowptr, (void*)&dinv,
                   (void*)&colx, (void*)&gb, (void*)&E, (void*)&N, (void*)&NB};
  hipLaunchCooperativeKernel((void*)k_prep, dim3(NBLK), dim3(1024), kargs, 0, stream);

  k_gemm<0><<<512, 256, 0, stream>>>(x, Wtg1, t, N);
  k_agg0<<<(N + 3) / 4, 256, 0, stream>>>(t, rowptr, colx, dinv, b1, h, N);
  k_gemm<1><<<512, 256, 0, stream>>>(h, Wtg2, t, N);
  int pwaves = (N + 7) / 8;
  k_aggp<<<(pwaves + 3) / 4, 256, 0, stream>>>(t, rowptr, colx, dinv, b2,
                                               bat, gb, N);
  k_mlp<<<NGRAPH, 512, 0, stream>>>(gb, bat, N, Wm1, bm1, Wm2, bm2, Wm3, bm3, out);
}

// Round 15
// 352.874 us; speedup vs baseline: 1.4227x; 1.4227x over previous
//
#include <hip/hip_runtime.h>

#define CDIM 128
#define NGRAPH 256
#define BSH 7                 // 128 nodes per bucket
#define BCAP 4096             // LDS sort capacity (mean 2048, +45 sigma)
#define NBLK 256              // blocks for two-pass scatter

typedef unsigned short bf16_t;
typedef __attribute__((ext_vector_type(8))) short bf16x8;  // MFMA A/B frag (4 VGPRs)
typedef __attribute__((ext_vector_type(4))) float f32x4;   // MFMA C/D frag

__device__ __forceinline__ float bflo(unsigned u) { return __uint_as_float(u << 16); }
__device__ __forceinline__ float bfhi(unsigned u) { return __uint_as_float(u & 0xffff0000u); }
__device__ __forceinline__ unsigned short f2bf(float f) {
  unsigned u = __float_as_uint(f);
  u += 0x7fffu + ((u >> 16) & 1u);   // round-to-nearest-even
  return (unsigned short)(u >> 16);
}

// ---------- W prep: fp32 [k][n] -> bf16 transposed [n][k], both layers ----------
__global__ __launch_bounds__(256) void k_wprep(const float* __restrict__ W1,
    const float* __restrict__ W2, bf16_t* __restrict__ Wtg1, bf16_t* __restrict__ Wtg2) {
  int i = blockIdx.x * 256 + threadIdx.x;   // 0..16383
  int n = i >> 7, k = i & 127;
  Wtg1[n * 128 + k] = f2bf(W1[k * 128 + n]);
  Wtg2[n * 128 + k] = f2bf(W2[k * 128 + n]);
}

// pass A: per-block LDS histogram over buckets -> phist[bucket*NBLK + blk]
__global__ __launch_bounds__(1024) void k_phist(const int* __restrict__ dst,
    int* __restrict__ phist, int E, int NB) {
  __shared__ int hist[1024];
  int t = blockIdx.x, tid = threadIdx.x;
  for (int i = tid; i < NB; i += 1024) hist[i] = 0;
  __syncthreads();
  int tile = (E + NBLK - 1) / NBLK;
  int lo = t * tile;
  int hi = lo + tile; if (hi > E) hi = E;
  for (int i = lo + tid; i < hi; i += 1024) atomicAdd(&hist[dst[i] >> BSH], 1);
  __syncthreads();
  for (int i = tid; i < NB; i += 1024) phist[i * NBLK + t] = hist[i];
}

// per-bucket scan: block b scans phist[b*NBLK .. +256] in place (exclusive),
// writes bucket total to btot[b].
__global__ __launch_bounds__(256) void k_bscan(int* __restrict__ phist,
    int* __restrict__ btot) {
  __shared__ int wsum[4];
  int b = blockIdx.x;
  int tid = threadIdx.x, lane = tid & 63, wave = tid >> 6;
  int orig = phist[b * NBLK + tid];
  int v = orig;
#pragma unroll
  for (int ofs = 1; ofs < 64; ofs <<= 1) {
    int u = __shfl_up(v, ofs, 64);
    if (lane >= ofs) v += u;
  }
  if (lane == 63) wsum[wave] = v;
  __syncthreads();
  int add = 0;
#pragma unroll
  for (int w = 0; w < 3; w++) if (w < wave) add += wsum[w];
  int incl = v + add;
  phist[b * NBLK + tid] = incl - orig;   // within-bucket exclusive offset
  if (tid == 255) btot[b] = incl;
}

// single-block exclusive scan of bucket totals -> bbase (bbase[NB] = E)
__global__ __launch_bounds__(1024) void k_boff(const int* __restrict__ bsums,
    int* __restrict__ boffs, int G) {
  __shared__ int sh[1024];
  int tid = threadIdx.x;
  int v = (tid < G) ? bsums[tid] : 0;
  sh[tid] = v;
  __syncthreads();
  for (int ofs = 1; ofs < 1024; ofs <<= 1) {
    int u = (tid >= ofs) ? sh[tid - ofs] : 0;
    __syncthreads();
    sh[tid] += u;
    __syncthreads();
  }
  if (tid < G) boffs[tid] = sh[tid] - v;
  if (tid == G) boffs[G] = (G > 0) ? sh[G - 1] : 0;
}

// pass B: exact-offset scatter, LDS cursors, zero global atomics.
__global__ __launch_bounds__(1024) void k_pscatter(const int* __restrict__ src,
    const int* __restrict__ dst, const int* __restrict__ phist,
    const int* __restrict__ bbase, unsigned* __restrict__ tmp, int E, int NB) {
  __shared__ int cur[1024];
  int t = blockIdx.x, tid = threadIdx.x;
  for (int i = tid; i < NB; i += 1024) cur[i] = bbase[i] + phist[i * NBLK + t];
  __syncthreads();
  int tile = (E + NBLK - 1) / NBLK;
  int lo = t * tile;
  int hi = lo + tile; if (hi > E) hi = E;
  for (int i = lo + tid; i < hi; i += 1024) {
    int d = dst[i];
    int p = atomicAdd(&cur[d >> BSH], 1);
    tmp[p] = (unsigned)src[i] | ((unsigned)(d & 127) << 20);
  }
}

// pass C: per-bucket LDS histogram + scan + counting sort; emits rowptr/dinv/col.
__global__ __launch_bounds__(256) void k_csort2(const unsigned* __restrict__ tmp,
    const int* __restrict__ bbase, int* __restrict__ rowptr, float* __restrict__ dinv,
    int* __restrict__ col, int N, int NB, int E) {
  __shared__ int hist[128];
  __shared__ int sc[128];
  __shared__ int lcur[128];
  __shared__ unsigned buf[BCAP];
  int b = blockIdx.x;
  int n0 = b << BSH;
  int base = bbase[b];
  int cnt = bbase[b + 1] - base;
  int tid = threadIdx.x;
  if (tid < 128) hist[tid] = 0;
  __syncthreads();
  for (int i = tid; i < cnt; i += 256) atomicAdd(&hist[(tmp[base + i] >> 20) & 127], 1);
  __syncthreads();
  if (tid < 128) sc[tid] = hist[tid];
  __syncthreads();
  for (int ofs = 1; ofs < 128; ofs <<= 1) {
    int v = (tid < 128 && tid >= ofs) ? sc[tid - ofs] : 0;
    __syncthreads();
    if (tid < 128) sc[tid] += v;
    __syncthreads();
  }
  if (tid < 128) {
    int excl = sc[tid] - hist[tid];
    lcur[tid] = excl;
    int node = n0 + tid;
    if (node < N) {
      rowptr[node] = base + excl;
      dinv[node] = rsqrtf((float)hist[tid] + 1.0f);
    }
  }
  if (b == 0 && tid == 0) rowptr[N] = E;
  __syncthreads();
  if (cnt <= BCAP) {
    for (int i = tid; i < cnt; i += 256) {
      unsigned pk = tmp[base + i];
      int p = atomicAdd(&lcur[(pk >> 20) & 127], 1);
      buf[p] = pk & 0xFFFFFu;
    }
    __syncthreads();
    for (int i = tid; i < cnt; i += 256) col[base + i] = (int)buf[i];
  } else {
    for (int i = tid; i < cnt; i += 256) {
      unsigned pk = tmp[base + i];
      int p = atomicAdd(&lcur[(pk >> 20) & 127], 1);
      col[base + p] = (int)(pk & 0xFFFFFu);
    }
  }
}

// ---------- MFMA GEMM: [M x 128] @ [128 x 128], bf16 MFMA, fp32 acc, bf16 out ----
#define WSTRIDE 136
template <int BF16IN>
__global__ __launch_bounds__(256) void k_gemm(const void* __restrict__ Ap,
    const bf16_t* __restrict__ Wtg, bf16_t* __restrict__ Co, int M) {
  __shared__ bf16_t Wt[128 * WSTRIDE];
  int tid = threadIdx.x;
  for (int c2 = tid; c2 < 2048; c2 += 256) {   // 2048 x 8-bf16 chunks
    int n = c2 >> 4;
    int k8 = (c2 & 15) << 3;
    *(uint4*)&Wt[n * WSTRIDE + k8] = *(const uint4*)&Wtg[n * 128 + k8];
  }
  __syncthreads();

  int wave = tid >> 6;
  int lane = tid & 63;
  int m = lane & 15;
  int q = lane >> 4;
  int nstrips = (M + 63) >> 6;

  for (int s = blockIdx.x; s < nstrips; s += gridDim.x) {
    int rowA = s * 64 + wave * 16 + m;
    if (rowA > M - 1) rowA = M - 1;
    bf16x8 a[4];
#pragma unroll
    for (int c = 0; c < 4; c++) {
      if (BF16IN) {
        a[c] = *(const bf16x8*)((const bf16_t*)Ap + (size_t)rowA * CDIM + c * 32 + q * 8);
      } else {
        const float* ap = (const float*)Ap + (size_t)rowA * CDIM + c * 32 + q * 8;
        float4 f0 = *(const float4*)ap;
        float4 f1 = *(const float4*)(ap + 4);
        union { bf16x8 v; unsigned short u[8]; } ua;
        ua.u[0] = f2bf(f0.x); ua.u[1] = f2bf(f0.y); ua.u[2] = f2bf(f0.z); ua.u[3] = f2bf(f0.w);
        ua.u[4] = f2bf(f1.x); ua.u[5] = f2bf(f1.y); ua.u[6] = f2bf(f1.z); ua.u[7] = f2bf(f1.w);
        a[c] = ua.v;
      }
    }
#pragma unroll
    for (int t = 0; t < 8; t++) {
      f32x4 acc = {0.f, 0.f, 0.f, 0.f};
#pragma unroll
      for (int c = 0; c < 4; c++) {
        bf16x8 bv = *(const bf16x8*)&Wt[(t * 16 + m) * WSTRIDE + c * 32 + q * 8];
        acc = __builtin_amdgcn_mfma_f32_16x16x32_bf16(a[c], bv, acc, 0, 0, 0);
      }
#pragma unroll
      for (int r = 0; r < 4; r++) {
        int row = s * 64 + wave * 16 + q * 4 + r;
        if (row < M) Co[(size_t)row * CDIM + t * 16 + m] = f2bf(acc[r]);
      }
    }
  }
}

// ---------- layer-1 gather aggregation (R9 structure: VGPR 24) ----------------
__global__ __launch_bounds__(256) void k_agg0(const bf16_t* __restrict__ t,
    const int* __restrict__ rowptr, const int* __restrict__ col,
    const float* __restrict__ dinv, const float* __restrict__ bias,
    bf16_t* __restrict__ out, int N) {
  int wave = threadIdx.x >> 6;
  int lane = threadIdx.x & 63;
  int node = blockIdx.x * 4 + wave;
  if (node >= N) return;
  int half = lane >> 5;
  int c = lane & 31;
  const uint2* tp = (const uint2*)t;
  float di = dinv[node];
  uint2 sv = tp[(size_t)node * 32 + c];
  float sw = (half == 0) ? di : 0.f;
  float a0 = bflo(sv.x) * sw, a1 = bfhi(sv.x) * sw;
  float a2 = bflo(sv.y) * sw, a3 = bfhi(sv.y) * sw;
  int beg = rowptr[node], end = rowptr[node + 1];
  for (int base = beg; base < end; base += 64) {
    int rem = end - base;
    int cnt = rem < 64 ? rem : 64;
    int sL = 0; float wL = 0.f;
    if (lane < cnt) { sL = col[base + lane]; wL = dinv[sL]; }
    for (int k = 0; k < cnt; k += 8) {
      int j0 = k + half, j1 = k + 2 + half, j2 = k + 4 + half, j3 = k + 6 + half;
      int s0 = __shfl(sL, j0, 64); float w0 = __shfl(wL, j0, 64);
      int s1 = __shfl(sL, j1, 64); float w1 = __shfl(wL, j1, 64);
      int s2 = __shfl(sL, j2, 64); float w2 = __shfl(wL, j2, 64);
      int s3 = __shfl(sL, j3, 64); float w3 = __shfl(wL, j3, 64);
      if (j0 >= cnt) { s0 = node; w0 = 0.f; }
      if (j1 >= cnt) { s1 = node; w1 = 0.f; }
      if (j2 >= cnt) { s2 = node; w2 = 0.f; }
      if (j3 >= cnt) { s3 = node; w3 = 0.f; }
      uint2 v0 = tp[(size_t)s0 * 32 + c];
      uint2 v1 = tp[(size_t)s1 * 32 + c];
      uint2 v2 = tp[(size_t)s2 * 32 + c];
      uint2 v3 = tp[(size_t)s3 * 32 + c];
      a0 = fmaf(bflo(v0.x), w0, a0); a1 = fmaf(bfhi(v0.x), w0, a1);
      a2 = fmaf(bflo(v0.y), w0, a2); a3 = fmaf(bfhi(v0.y), w0, a3);
      a0 = fmaf(bflo(v1.x), w1, a0); a1 = fmaf(bfhi(v1.x), w1, a1);
      a2 = fmaf(bflo(v1.y), w1, a2); a3 = fmaf(bfhi(v1.y), w1, a3);
      a0 = fmaf(bflo(v2.x), w2, a0); a1 = fmaf(bfhi(v2.x), w2, a1);
      a2 = fmaf(bflo(v2.y), w2, a2); a3 = fmaf(bfhi(v2.y), w2, a3);
      a0 = fmaf(bflo(v3.x), w3, a0); a1 = fmaf(bfhi(v3.x), w3, a1);
      a2 = fmaf(bflo(v3.y), w3, a2); a3 = fmaf(bfhi(v3.y), w3, a3);
    }
  }
  a0 += __shfl_xor(a0, 32, 64);
  a1 += __shfl_xor(a1, 32, 64);
  a2 += __shfl_xor(a2, 32, 64);
  a3 += __shfl_xor(a3, 32, 64);
  if (half == 0) {
    float4 bb = ((const float4*)bias)[c];
    float o0 = fmaxf(fmaf(di, a0, bb.x), 0.f);
    float o1 = fmaxf(fmaf(di, a1, bb.y), 0.f);
    float o2 = fmaxf(fmaf(di, a2, bb.z), 0.f);
    float o3 = fmaxf(fmaf(di, a3, bb.w), 0.f);
    uint2 o;
    o.x = ((unsigned)f2bf(o1) << 16) | f2bf(o0);
    o.y = ((unsigned)f2bf(o3) << 16) | f2bf(o2);
    ((uint2*)(out + (size_t)node * CDIM))[c] = o;
  }
}

// ---------- layer-2 gather aggregation fused with mean-pool -------------------
// 8 consecutive nodes per wave (16/wave was wave-starved: 6250 waves < 8192
// slots, occ 51% — R13). Pooled sums in registers; atomic flush on graph change.
__global__ __launch_bounds__(256) void k_aggp(const bf16_t* __restrict__ t,
    const int* __restrict__ rowptr, const int* __restrict__ col,
    const float* __restrict__ dinv, const float* __restrict__ bias,
    const int* __restrict__ batch, float* __restrict__ gsum, int N) {
  int wave = threadIdx.x >> 6;
  int lane = threadIdx.x & 63;
  int half = lane >> 5;
  int c = lane & 31;
  const uint2* tp = (const uint2*)t;
  float4 bb = ((const float4*)bias)[c];
  int n0 = (blockIdx.x * 4 + wave) * 8;
  if (n0 >= N) return;
  int nEnd = n0 + 8; if (nEnd > N) nEnd = N;
  float p0 = 0.f, p1 = 0.f, p2 = 0.f, p3 = 0.f;
  int curb = batch[n0];

  for (int node = n0; node < nEnd; node++) {
    float di = dinv[node];
    uint2 sv = tp[(size_t)node * 32 + c];
    float sw = (half == 0) ? di : 0.f;
    float a0 = bflo(sv.x) * sw, a1 = bfhi(sv.x) * sw;
    float a2 = bflo(sv.y) * sw, a3 = bfhi(sv.y) * sw;
    int beg = rowptr[node], end = rowptr[node + 1];
    for (int base = beg; base < end; base += 64) {
      int rem = end - base;
      int cnt = rem < 64 ? rem : 64;
      int sL = 0; float wL = 0.f;
      if (lane < cnt) { sL = col[base + lane]; wL = dinv[sL]; }
      for (int k = 0; k < cnt; k += 8) {
        int j0 = k + half, j1 = k + 2 + half, j2 = k + 4 + half, j3 = k + 6 + half;
        int s0 = __shfl(sL, j0, 64); float w0 = __shfl(wL, j0, 64);
        int s1 = __shfl(sL, j1, 64); float w1 = __shfl(wL, j1, 64);
        int s2 = __shfl(sL, j2, 64); float w2 = __shfl(wL, j2, 64);
        int s3 = __shfl(sL, j3, 64); float w3 = __shfl(wL, j3, 64);
        if (j0 >= cnt) { s0 = node; w0 = 0.f; }
        if (j1 >= cnt) { s1 = node; w1 = 0.f; }
        if (j2 >= cnt) { s2 = node; w2 = 0.f; }
        if (j3 >= cnt) { s3 = node; w3 = 0.f; }
        uint2 v0 = tp[(size_t)s0 * 32 + c];
        uint2 v1 = tp[(size_t)s1 * 32 + c];
        uint2 v2 = tp[(size_t)s2 * 32 + c];
        uint2 v3 = tp[(size_t)s3 * 32 + c];
        a0 = fmaf(bflo(v0.x), w0, a0); a1 = fmaf(bfhi(v0.x), w0, a1);
        a2 = fmaf(bflo(v0.y), w0, a2); a3 = fmaf(bfhi(v0.y), w0, a3);
        a0 = fmaf(bflo(v1.x), w1, a0); a1 = fmaf(bfhi(v1.x), w1, a1);
        a2 = fmaf(bflo(v1.y), w1, a2); a3 = fmaf(bfhi(v1.y), w1, a3);
        a0 = fmaf(bflo(v2.x), w2, a0); a1 = fmaf(bfhi(v2.x), w2, a1);
        a2 = fmaf(bflo(v2.y), w2, a2); a3 = fmaf(bfhi(v2.y), w2, a3);
        a0 = fmaf(bflo(v3.x), w3, a0); a1 = fmaf(bfhi(v3.x), w3, a1);
        a2 = fmaf(bflo(v3.y), w3, a2); a3 = fmaf(bfhi(v3.y), w3, a3);
      }
    }
    a0 += __shfl_xor(a0, 32, 64);
    a1 += __shfl_xor(a1, 32, 64);
    a2 += __shfl_xor(a2, 32, 64);
    a3 += __shfl_xor(a3, 32, 64);
    if (half == 0) {
      float o0 = fmaxf(fmaf(di, a0, bb.x), 0.f);
      float o1 = fmaxf(fmaf(di, a1, bb.y), 0.f);
      float o2 = fmaxf(fmaf(di, a2, bb.z), 0.f);
      float o3 = fmaxf(fmaf(di, a3, bb.w), 0.f);
      int b = batch[node];
      if (b != curb) {
        atomicAdd(&gsum[curb * CDIM + c * 4 + 0], p0);
        atomicAdd(&gsum[curb * CDIM + c * 4 + 1], p1);
        atomicAdd(&gsum[curb * CDIM + c * 4 + 2], p2);
        atomicAdd(&gsum[curb * CDIM + c * 4 + 3], p3);
        curb = b; p0 = p1 = p2 = p3 = 0.f;
      }
      p0 += __uint_as_float((unsigned)f2bf(o0) << 16);
      p1 += __uint_as_float((unsigned)f2bf(o1) << 16);
      p2 += __uint_as_float((unsigned)f2bf(o2) << 16);
      p3 += __uint_as_float((unsigned)f2bf(o3) << 16);
    }
  }
  if (half == 0) {
    atomicAdd(&gsum[curb * CDIM + c * 4 + 0], p0);
    atomicAdd(&gsum[curb * CDIM + c * 4 + 1], p1);
    atomicAdd(&gsum[curb * CDIM + c * 4 + 2], p2);
    atomicAdd(&gsum[curb * CDIM + c * 4 + 3], p3);
  }
}

// ---------- fused MLP head: pool-divide + mlp1 + mlp2 + mlp3 ------------------
__global__ __launch_bounds__(512) void k_mlp(const float* __restrict__ g,
    const int* __restrict__ batch, int N,
    const float* __restrict__ Wm1, const float* __restrict__ bm1,
    const float* __restrict__ Wm2, const float* __restrict__ bm2,
    const float* __restrict__ wm3, const float* __restrict__ bm3,
    float* __restrict__ out) {
  __shared__ float gs[CDIM];
  __shared__ float m1s[500];
  __shared__ float m2s[100];
  int bi = blockIdx.x, tid = threadIdx.x;
  if (tid < CDIM) {
    int lo = 0, hi = N;
    while (lo < hi) { int mid = (lo + hi) >> 1; if (batch[mid] < bi) lo = mid + 1; else hi = mid; }
    int s = lo;
    lo = 0; hi = N;
    int key = bi + 1;
    while (lo < hi) { int mid = (lo + hi) >> 1; if (batch[mid] < key) lo = mid + 1; else hi = mid; }
    float inv = 1.f / fmaxf((float)(lo - s), 1.f);
    gs[tid] = g[bi * CDIM + tid] * inv;
  }
  __syncthreads();
  if (tid < 500) {
    float acc = bm1[tid];
#pragma unroll 4
    for (int k = 0; k < CDIM; k++) acc = fmaf(gs[k], Wm1[k * 500 + tid], acc);
    m1s[tid] = fmaxf(acc, 0.f);
  }
  __syncthreads();
  if (tid < 100) {
    float acc = bm2[tid];
    for (int k = 0; k < 500; k++) acc = fmaf(m1s[k], Wm2[k * 100 + tid], acc);
    m2s[tid] = fmaxf(acc, 0.f) * wm3[tid];
  }
  __syncthreads();
  if (tid < 64) {
    float v = m2s[tid] + ((tid + 64 < 100) ? m2s[tid + 64] : 0.f);
#pragma unroll
    for (int ofs = 32; ofs > 0; ofs >>= 1) v += __shfl_down(v, ofs, 64);
    if (tid == 0) out[bi] = v + bm3[0];
  }
}

static inline size_t align_up(size_t v) { return (v + 255) & ~(size_t)255; }

extern "C" void kernel_launch(void* const* d_in, const int* in_sizes, int n_in,
                              void* d_out, int out_size, void* d_ws, size_t ws_size,
                              hipStream_t stream) {
  const float* x   = (const float*)d_in[0];
  const int*   ei  = (const int*)d_in[1];
  const int*   bat = (const int*)d_in[2];
  const float* W1  = (const float*)d_in[3];
  const float* b1  = (const float*)d_in[4];
  const float* W2  = (const float*)d_in[5];
  const float* b2  = (const float*)d_in[6];
  const float* Wm1 = (const float*)d_in[7];
  const float* bm1 = (const float*)d_in[8];
  const float* Wm2 = (const float*)d_in[9];
  const float* bm2 = (const float*)d_in[10];
  const float* Wm3 = (const float*)d_in[11];
  const float* bm3 = (const float*)d_in[12];
  float* out = (float*)d_out;

  const int E = in_sizes[1] / 2;
  const int N = in_sizes[2];
  const int* src = ei;
  const int* dst = ei + E;
  const int NB = (N + 127) >> BSH;
  const int M  = NB * NBLK;              // phist elements

  char* p = (char*)d_ws;
  bf16_t* t    = (bf16_t*)p;   p += align_up((size_t)N * CDIM * 2);
  bf16_t* h    = (bf16_t*)p;   p += align_up((size_t)N * CDIM * 2);
  int* rowptr  = (int*)p;      p += align_up((size_t)(N + 1) * 4);
  int* colx    = (int*)p;      p += align_up((size_t)E * 4);
  unsigned* tmp= (unsigned*)p; p += align_up((size_t)E * 4);
  float* dinv  = (float*)p;    p += align_up((size_t)N * 4);
  int* phist   = (int*)p;      p += align_up((size_t)M * 4);
  int* btot    = (int*)p;      p += align_up((size_t)NB * 4);
  int* bbase   = (int*)p;      p += align_up((size_t)(NB + 1) * 4);
  bf16_t* Wtg1 = (bf16_t*)p;   p += align_up((size_t)CDIM * CDIM * 2);
  bf16_t* Wtg2 = (bf16_t*)p;   p += align_up((size_t)CDIM * CDIM * 2);
  float* gb    = (float*)p;    p += align_up((size_t)NGRAPH * CDIM * 4);
  (void)ws_size; (void)n_in; (void)out_size;

  hipMemsetAsync(gb, 0, (size_t)NGRAPH * CDIM * 4, stream);

  k_wprep<<<64, 256, 0, stream>>>(W1, W2, Wtg1, Wtg2);
  k_phist<<<NBLK, 1024, 0, stream>>>(dst, phist, E, NB);
  k_bscan<<<NB, 256, 0, stream>>>(phist, btot);
  k_boff<<<1, 1024, 0, stream>>>(btot, bbase, NB);
  k_pscatter<<<NBLK, 1024, 0, stream>>>(src, dst, phist, bbase, tmp, E, NB);
  k_csort2<<<NB, 256, 0, stream>>>(tmp, bbase, rowptr, dinv, colx, N, NB, E);

  k_gemm<0><<<512, 256, 0, stream>>>(x, Wtg1, t, N);
  k_agg0<<<(N + 3) / 4, 256, 0, stream>>>(t, rowptr, colx, dinv, b1, h, N);
  k_gemm<1><<<512, 256, 0, stream>>>(h, Wtg2, t, N);
  int pwaves = (N + 7) / 8;
  k_aggp<<<(pwaves + 3) / 4, 256, 0, stream>>>(t, rowptr, colx, dinv, b2,
                                               bat, gb, N);
  k_mlp<<<NGRAPH, 512, 0, stream>>>(gb, bat, N, Wm1, bm1, Wm2, bm2, Wm3, bm3, out);
}

// Round 16
// 344.048 us; speedup vs baseline: 1.4592x; 1.0257x over previous
//
#include <hip/hip_runtime.h>

#define CDIM 128
#define NGRAPH 256
#define BSH 7                 // 128 nodes per bucket
#define BCAP 4096             // LDS sort capacity (mean 2048, +45 sigma)
#define NBLK 256              // blocks for two-pass scatter

typedef unsigned short bf16_t;
typedef __attribute__((ext_vector_type(8))) short bf16x8;  // MFMA A/B frag (4 VGPRs)
typedef __attribute__((ext_vector_type(4))) float f32x4;   // MFMA C/D frag

__device__ __forceinline__ float bflo(unsigned u) { return __uint_as_float(u << 16); }
__device__ __forceinline__ float bfhi(unsigned u) { return __uint_as_float(u & 0xffff0000u); }
__device__ __forceinline__ unsigned short f2bf(float f) {
  unsigned u = __float_as_uint(f);
  u += 0x7fffu + ((u >> 16) & 1u);   // round-to-nearest-even
  return (unsigned short)(u >> 16);
}

// pass A + prologue: W transpose->bf16, gb zero-init, per-block bucket histogram.
// The three pieces touch disjoint outputs and need no inter-block ordering.
__global__ __launch_bounds__(1024) void k_phist(const int* __restrict__ dst,
    int* __restrict__ phist, const float* __restrict__ W1,
    const float* __restrict__ W2, bf16_t* __restrict__ Wtg1,
    bf16_t* __restrict__ Wtg2, float* __restrict__ gb, int E, int NB) {
  __shared__ int hist[1024];
  int t = blockIdx.x, tid = threadIdx.x;
  int gidx = t * 1024 + tid;
  if (gidx < 16384) {                       // W prep (blocks 0..15)
    int n = gidx >> 7, k = gidx & 127;
    Wtg1[n * 128 + k] = f2bf(W1[k * 128 + n]);
    Wtg2[n * 128 + k] = f2bf(W2[k * 128 + n]);
  }
  if (gidx < NGRAPH * CDIM) gb[gidx] = 0.f; // gb zero (blocks 0..31)
  for (int i = tid; i < NB; i += 1024) hist[i] = 0;
  __syncthreads();
  int tile = (E + NBLK - 1) / NBLK;
  int lo = t * tile;
  int hi = lo + tile; if (hi > E) hi = E;
  for (int i = lo + tid; i < hi; i += 1024) atomicAdd(&hist[dst[i] >> BSH], 1);
  __syncthreads();
  for (int i = tid; i < NB; i += 1024) phist[i * NBLK + t] = hist[i];
}

// per-bucket scan: block b scans phist[b*NBLK .. +256] in place (exclusive),
// writes bucket total to btot[b].
__global__ __launch_bounds__(256) void k_bscan(int* __restrict__ phist,
    int* __restrict__ btot) {
  __shared__ int wsum[4];
  int b = blockIdx.x;
  int tid = threadIdx.x, lane = tid & 63, wave = tid >> 6;
  int orig = phist[b * NBLK + tid];
  int v = orig;
#pragma unroll
  for (int ofs = 1; ofs < 64; ofs <<= 1) {
    int u = __shfl_up(v, ofs, 64);
    if (lane >= ofs) v += u;
  }
  if (lane == 63) wsum[wave] = v;
  __syncthreads();
  int add = 0;
#pragma unroll
  for (int w = 0; w < 3; w++) if (w < wave) add += wsum[w];
  int incl = v + add;
  phist[b * NBLK + tid] = incl - orig;   // within-bucket exclusive offset
  if (tid == 255) btot[b] = incl;
}

// single-block exclusive scan of bucket totals -> bbase (bbase[NB] = E)
__global__ __launch_bounds__(1024) void k_boff(const int* __restrict__ bsums,
    int* __restrict__ boffs, int G) {
  __shared__ int sh[1024];
  int tid = threadIdx.x;
  int v = (tid < G) ? bsums[tid] : 0;
  sh[tid] = v;
  __syncthreads();
  for (int ofs = 1; ofs < 1024; ofs <<= 1) {
    int u = (tid >= ofs) ? sh[tid - ofs] : 0;
    __syncthreads();
    sh[tid] += u;
    __syncthreads();
  }
  if (tid < G) boffs[tid] = sh[tid] - v;
  if (tid == G) boffs[G] = (G > 0) ? sh[G - 1] : 0;
}

// pass B: exact-offset scatter, LDS cursors, zero global atomics.
__global__ __launch_bounds__(1024) void k_pscatter(const int* __restrict__ src,
    const int* __restrict__ dst, const int* __restrict__ phist,
    const int* __restrict__ bbase, unsigned* __restrict__ tmp, int E, int NB) {
  __shared__ int cur[1024];
  int t = blockIdx.x, tid = threadIdx.x;
  for (int i = tid; i < NB; i += 1024) cur[i] = bbase[i] + phist[i * NBLK + t];
  __syncthreads();
  int tile = (E + NBLK - 1) / NBLK;
  int lo = t * tile;
  int hi = lo + tile; if (hi > E) hi = E;
  for (int i = lo + tid; i < hi; i += 1024) {
    int d = dst[i];
    int p = atomicAdd(&cur[d >> BSH], 1);
    tmp[p] = (unsigned)src[i] | ((unsigned)(d & 127) << 20);
  }
}

// pass C: per-bucket LDS histogram + scan + counting sort; emits rowptr/dinv/col.
__global__ __launch_bounds__(256) void k_csort2(const unsigned* __restrict__ tmp,
    const int* __restrict__ bbase, int* __restrict__ rowptr, float* __restrict__ dinv,
    int* __restrict__ col, int N, int NB, int E) {
  __shared__ int hist[128];
  __shared__ int sc[128];
  __shared__ int lcur[128];
  __shared__ unsigned buf[BCAP];
  int b = blockIdx.x;
  int n0 = b << BSH;
  int base = bbase[b];
  int cnt = bbase[b + 1] - base;
  int tid = threadIdx.x;
  if (tid < 128) hist[tid] = 0;
  __syncthreads();
  for (int i = tid; i < cnt; i += 256) atomicAdd(&hist[(tmp[base + i] >> 20) & 127], 1);
  __syncthreads();
  if (tid < 128) sc[tid] = hist[tid];
  __syncthreads();
  for (int ofs = 1; ofs < 128; ofs <<= 1) {
    int v = (tid < 128 && tid >= ofs) ? sc[tid - ofs] : 0;
    __syncthreads();
    if (tid < 128) sc[tid] += v;
    __syncthreads();
  }
  if (tid < 128) {
    int excl = sc[tid] - hist[tid];
    lcur[tid] = excl;
    int node = n0 + tid;
    if (node < N) {
      rowptr[node] = base + excl;
      dinv[node] = rsqrtf((float)hist[tid] + 1.0f);
    }
  }
  if (b == 0 && tid == 0) rowptr[N] = E;
  __syncthreads();
  if (cnt <= BCAP) {
    for (int i = tid; i < cnt; i += 256) {
      unsigned pk = tmp[base + i];
      int p = atomicAdd(&lcur[(pk >> 20) & 127], 1);
      buf[p] = pk & 0xFFFFFu;
    }
    __syncthreads();
    for (int i = tid; i < cnt; i += 256) col[base + i] = (int)buf[i];
  } else {
    for (int i = tid; i < cnt; i += 256) {
      unsigned pk = tmp[base + i];
      int p = atomicAdd(&lcur[(pk >> 20) & 127], 1);
      col[base + p] = (int)(pk & 0xFFFFFu);
    }
  }
}

// ---------- MFMA GEMM: [M x 128] @ [128 x 128], bf16 MFMA, fp32 acc, bf16 out ----
#define WSTRIDE 136
template <int BF16IN>
__global__ __launch_bounds__(256) void k_gemm(const void* __restrict__ Ap,
    const bf16_t* __restrict__ Wtg, bf16_t* __restrict__ Co, int M) {
  __shared__ bf16_t Wt[128 * WSTRIDE];
  int tid = threadIdx.x;
  for (int c2 = tid; c2 < 2048; c2 += 256) {   // 2048 x 8-bf16 chunks
    int n = c2 >> 4;
    int k8 = (c2 & 15) << 3;
    *(uint4*)&Wt[n * WSTRIDE + k8] = *(const uint4*)&Wtg[n * 128 + k8];
  }
  __syncthreads();

  int wave = tid >> 6;
  int lane = tid & 63;
  int m = lane & 15;
  int q = lane >> 4;
  int nstrips = (M + 63) >> 6;

  for (int s = blockIdx.x; s < nstrips; s += gridDim.x) {
    int rowA = s * 64 + wave * 16 + m;
    if (rowA > M - 1) rowA = M - 1;
    bf16x8 a[4];
#pragma unroll
    for (int c = 0; c < 4; c++) {
      if (BF16IN) {
        a[c] = *(const bf16x8*)((const bf16_t*)Ap + (size_t)rowA * CDIM + c * 32 + q * 8);
      } else {
        const float* ap = (const float*)Ap + (size_t)rowA * CDIM + c * 32 + q * 8;
        float4 f0 = *(const float4*)ap;
        float4 f1 = *(const float4*)(ap + 4);
        union { bf16x8 v; unsigned short u[8]; } ua;
        ua.u[0] = f2bf(f0.x); ua.u[1] = f2bf(f0.y); ua.u[2] = f2bf(f0.z); ua.u[3] = f2bf(f0.w);
        ua.u[4] = f2bf(f1.x); ua.u[5] = f2bf(f1.y); ua.u[6] = f2bf(f1.z); ua.u[7] = f2bf(f1.w);
        a[c] = ua.v;
      }
    }
#pragma unroll
    for (int t = 0; t < 8; t++) {
      f32x4 acc = {0.f, 0.f, 0.f, 0.f};
#pragma unroll
      for (int c = 0; c < 4; c++) {
        bf16x8 bv = *(const bf16x8*)&Wt[(t * 16 + m) * WSTRIDE + c * 32 + q * 8];
        acc = __builtin_amdgcn_mfma_f32_16x16x32_bf16(a[c], bv, acc, 0, 0, 0);
      }
#pragma unroll
      for (int r = 0; r < 4; r++) {
        int row = s * 64 + wave * 16 + q * 4 + r;
        if (row < M) Co[(size_t)row * CDIM + t * 16 + m] = f2bf(acc[r]);
      }
    }
  }
}

// ---------- layer-1 gather aggregation (R9 structure: VGPR 24) ----------------
__global__ __launch_bounds__(256) void k_agg0(const bf16_t* __restrict__ t,
    const int* __restrict__ rowptr, const int* __restrict__ col,
    const float* __restrict__ dinv, const float* __restrict__ bias,
    bf16_t* __restrict__ out, int N) {
  int wave = threadIdx.x >> 6;
  int lane = threadIdx.x & 63;
  int node = blockIdx.x * 4 + wave;
  if (node >= N) return;
  int half = lane >> 5;
  int c = lane & 31;
  const uint2* tp = (const uint2*)t;
  float di = dinv[node];
  uint2 sv = tp[(size_t)node * 32 + c];
  float sw = (half == 0) ? di : 0.f;
  float a0 = bflo(sv.x) * sw, a1 = bfhi(sv.x) * sw;
  float a2 = bflo(sv.y) * sw, a3 = bfhi(sv.y) * sw;
  int beg = rowptr[node], end = rowptr[node + 1];
  for (int base = beg; base < end; base += 64) {
    int rem = end - base;
    int cnt = rem < 64 ? rem : 64;
    int sL = 0; float wL = 0.f;
    if (lane < cnt) { sL = col[base + lane]; wL = dinv[sL]; }
    for (int k = 0; k < cnt; k += 8) {
      int j0 = k + half, j1 = k + 2 + half, j2 = k + 4 + half, j3 = k + 6 + half;
      int s0 = __shfl(sL, j0, 64); float w0 = __shfl(wL, j0, 64);
      int s1 = __shfl(sL, j1, 64); float w1 = __shfl(wL, j1, 64);
      int s2 = __shfl(sL, j2, 64); float w2 = __shfl(wL, j2, 64);
      int s3 = __shfl(sL, j3, 64); float w3 = __shfl(wL, j3, 64);
      if (j0 >= cnt) { s0 = node; w0 = 0.f; }
      if (j1 >= cnt) { s1 = node; w1 = 0.f; }
      if (j2 >= cnt) { s2 = node; w2 = 0.f; }
      if (j3 >= cnt) { s3 = node; w3 = 0.f; }
      uint2 v0 = tp[(size_t)s0 * 32 + c];
      uint2 v1 = tp[(size_t)s1 * 32 + c];
      uint2 v2 = tp[(size_t)s2 * 32 + c];
      uint2 v3 = tp[(size_t)s3 * 32 + c];
      a0 = fmaf(bflo(v0.x), w0, a0); a1 = fmaf(bfhi(v0.x), w0, a1);
      a2 = fmaf(bflo(v0.y), w0, a2); a3 = fmaf(bfhi(v0.y), w0, a3);
      a0 = fmaf(bflo(v1.x), w1, a0); a1 = fmaf(bfhi(v1.x), w1, a1);
      a2 = fmaf(bflo(v1.y), w1, a2); a3 = fmaf(bfhi(v1.y), w1, a3);
      a0 = fmaf(bflo(v2.x), w2, a0); a1 = fmaf(bfhi(v2.x), w2, a1);
      a2 = fmaf(bflo(v2.y), w2, a2); a3 = fmaf(bfhi(v2.y), w2, a3);
      a0 = fmaf(bflo(v3.x), w3, a0); a1 = fmaf(bfhi(v3.x), w3, a1);
      a2 = fmaf(bflo(v3.y), w3, a2); a3 = fmaf(bfhi(v3.y), w3, a3);
    }
  }
  a0 += __shfl_xor(a0, 32, 64);
  a1 += __shfl_xor(a1, 32, 64);
  a2 += __shfl_xor(a2, 32, 64);
  a3 += __shfl_xor(a3, 32, 64);
  if (half == 0) {
    float4 bb = ((const float4*)bias)[c];
    float o0 = fmaxf(fmaf(di, a0, bb.x), 0.f);
    float o1 = fmaxf(fmaf(di, a1, bb.y), 0.f);
    float o2 = fmaxf(fmaf(di, a2, bb.z), 0.f);
    float o3 = fmaxf(fmaf(di, a3, bb.w), 0.f);
    uint2 o;
    o.x = ((unsigned)f2bf(o1) << 16) | f2bf(o0);
    o.y = ((unsigned)f2bf(o3) << 16) | f2bf(o2);
    ((uint2*)(out + (size_t)node * CDIM))[c] = o;
  }
}

// ---------- layer-2 gather aggregation fused with mean-pool -------------------
// 16 consecutive nodes per wave (R13-proven; 8/wave doubled atomic flush
// traffic 13->25 MB and regressed — R15). Pooled sums in registers.
__global__ __launch_bounds__(256) void k_aggp(const bf16_t* __restrict__ t,
    const int* __restrict__ rowptr, const int* __restrict__ col,
    const float* __restrict__ dinv, const float* __restrict__ bias,
    const int* __restrict__ batch, float* __restrict__ gsum, int N) {
  int wave = threadIdx.x >> 6;
  int lane = threadIdx.x & 63;
  int half = lane >> 5;
  int c = lane & 31;
  const uint2* tp = (const uint2*)t;
  float4 bb = ((const float4*)bias)[c];
  int n0 = (blockIdx.x * 4 + wave) * 16;
  if (n0 >= N) return;
  int nEnd = n0 + 16; if (nEnd > N) nEnd = N;
  float p0 = 0.f, p1 = 0.f, p2 = 0.f, p3 = 0.f;
  int curb = batch[n0];

  for (int node = n0; node < nEnd; node++) {
    float di = dinv[node];
    uint2 sv = tp[(size_t)node * 32 + c];
    float sw = (half == 0) ? di : 0.f;
    float a0 = bflo(sv.x) * sw, a1 = bfhi(sv.x) * sw;
    float a2 = bflo(sv.y) * sw, a3 = bfhi(sv.y) * sw;
    int beg = rowptr[node], end = rowptr[node + 1];
    for (int base = beg; base < end; base += 64) {
      int rem = end - base;
      int cnt = rem < 64 ? rem : 64;
      int sL = 0; float wL = 0.f;
      if (lane < cnt) { sL = col[base + lane]; wL = dinv[sL]; }
      for (int k = 0; k < cnt; k += 8) {
        int j0 = k + half, j1 = k + 2 + half, j2 = k + 4 + half, j3 = k + 6 + half;
        int s0 = __shfl(sL, j0, 64); float w0 = __shfl(wL, j0, 64);
        int s1 = __shfl(sL, j1, 64); float w1 = __shfl(wL, j1, 64);
        int s2 = __shfl(sL, j2, 64); float w2 = __shfl(wL, j2, 64);
        int s3 = __shfl(sL, j3, 64); float w3 = __shfl(wL, j3, 64);
        if (j0 >= cnt) { s0 = node; w0 = 0.f; }
        if (j1 >= cnt) { s1 = node; w1 = 0.f; }
        if (j2 >= cnt) { s2 = node; w2 = 0.f; }
        if (j3 >= cnt) { s3 = node; w3 = 0.f; }
        uint2 v0 = tp[(size_t)s0 * 32 + c];
        uint2 v1 = tp[(size_t)s1 * 32 + c];
        uint2 v2 = tp[(size_t)s2 * 32 + c];
        uint2 v3 = tp[(size_t)s3 * 32 + c];
        a0 = fmaf(bflo(v0.x), w0, a0); a1 = fmaf(bfhi(v0.x), w0, a1);
        a2 = fmaf(bflo(v0.y), w0, a2); a3 = fmaf(bfhi(v0.y), w0, a3);
        a0 = fmaf(bflo(v1.x), w1, a0); a1 = fmaf(bfhi(v1.x), w1, a1);
        a2 = fmaf(bflo(v1.y), w1, a2); a3 = fmaf(bfhi(v1.y), w1, a3);
        a0 = fmaf(bflo(v2.x), w2, a0); a1 = fmaf(bfhi(v2.x), w2, a1);
        a2 = fmaf(bflo(v2.y), w2, a2); a3 = fmaf(bfhi(v2.y), w2, a3);
        a0 = fmaf(bflo(v3.x), w3, a0); a1 = fmaf(bfhi(v3.x), w3, a1);
        a2 = fmaf(bflo(v3.y), w3, a2); a3 = fmaf(bfhi(v3.y), w3, a3);
      }
    }
    a0 += __shfl_xor(a0, 32, 64);
    a1 += __shfl_xor(a1, 32, 64);
    a2 += __shfl_xor(a2, 32, 64);
    a3 += __shfl_xor(a3, 32, 64);
    if (half == 0) {
      float o0 = fmaxf(fmaf(di, a0, bb.x), 0.f);
      float o1 = fmaxf(fmaf(di, a1, bb.y), 0.f);
      float o2 = fmaxf(fmaf(di, a2, bb.z), 0.f);
      float o3 = fmaxf(fmaf(di, a3, bb.w), 0.f);
      int b = batch[node];
      if (b != curb) {
        atomicAdd(&gsum[curb * CDIM + c * 4 + 0], p0);
        atomicAdd(&gsum[curb * CDIM + c * 4 + 1], p1);
        atomicAdd(&gsum[curb * CDIM + c * 4 + 2], p2);
        atomicAdd(&gsum[curb * CDIM + c * 4 + 3], p3);
        curb = b; p0 = p1 = p2 = p3 = 0.f;
      }
      p0 += __uint_as_float((unsigned)f2bf(o0) << 16);
      p1 += __uint_as_float((unsigned)f2bf(o1) << 16);
      p2 += __uint_as_float((unsigned)f2bf(o2) << 16);
      p3 += __uint_as_float((unsigned)f2bf(o3) << 16);
    }
  }
  if (half == 0) {
    atomicAdd(&gsum[curb * CDIM + c * 4 + 0], p0);
    atomicAdd(&gsum[curb * CDIM + c * 4 + 1], p1);
    atomicAdd(&gsum[curb * CDIM + c * 4 + 2], p2);
    atomicAdd(&gsum[curb * CDIM + c * 4 + 3], p3);
  }
}

// ---------- fused MLP head: pool-divide + mlp1 + mlp2 + mlp3 ------------------
__global__ __launch_bounds__(512) void k_mlp(const float* __restrict__ g,
    const int* __restrict__ batch, int N,
    const float* __restrict__ Wm1, const float* __restrict__ bm1,
    const float* __restrict__ Wm2, const float* __restrict__ bm2,
    const float* __restrict__ wm3, const float* __restrict__ bm3,
    float* __restrict__ out) {
  __shared__ float gs[CDIM];
  __shared__ float m1s[500];
  __shared__ float m2s[100];
  int bi = blockIdx.x, tid = threadIdx.x;
  if (tid < CDIM) {
    int lo = 0, hi = N;
    while (lo < hi) { int mid = (lo + hi) >> 1; if (batch[mid] < bi) lo = mid + 1; else hi = mid; }
    int s = lo;
    lo = 0; hi = N;
    int key = bi + 1;
    while (lo < hi) { int mid = (lo + hi) >> 1; if (batch[mid] < key) lo = mid + 1; else hi = mid; }
    float inv = 1.f / fmaxf((float)(lo - s), 1.f);
    gs[tid] = g[bi * CDIM + tid] * inv;
  }
  __syncthreads();
  if (tid < 500) {
    float acc = bm1[tid];
#pragma unroll 4
    for (int k = 0; k < CDIM; k++) acc = fmaf(gs[k], Wm1[k * 500 + tid], acc);
    m1s[tid] = fmaxf(acc, 0.f);
  }
  __syncthreads();
  if (tid < 100) {
    float acc = bm2[tid];
    for (int k = 0; k < 500; k++) acc = fmaf(m1s[k], Wm2[k * 100 + tid], acc);
    m2s[tid] = fmaxf(acc, 0.f) * wm3[tid];
  }
  __syncthreads();
  if (tid < 64) {
    float v = m2s[tid] + ((tid + 64 < 100) ? m2s[tid + 64] : 0.f);
#pragma unroll
    for (int ofs = 32; ofs > 0; ofs >>= 1) v += __shfl_down(v, ofs, 64);
    if (tid == 0) out[bi] = v + bm3[0];
  }
}

static inline size_t align_up(size_t v) { return (v + 255) & ~(size_t)255; }

extern "C" void kernel_launch(void* const* d_in, const int* in_sizes, int n_in,
                              void* d_out, int out_size, void* d_ws, size_t ws_size,
                              hipStream_t stream) {
  const float* x   = (const float*)d_in[0];
  const int*   ei  = (const int*)d_in[1];
  const int*   bat = (const int*)d_in[2];
  const float* W1  = (const float*)d_in[3];
  const float* b1  = (const float*)d_in[4];
  const float* W2  = (const float*)d_in[5];
  const float* b2  = (const float*)d_in[6];
  const float* Wm1 = (const float*)d_in[7];
  const float* bm1 = (const float*)d_in[8];
  const float* Wm2 = (const float*)d_in[9];
  const float* bm2 = (const float*)d_in[10];
  const float* Wm3 = (const float*)d_in[11];
  const float* bm3 = (const float*)d_in[12];
  float* out = (float*)d_out;

  const int E = in_sizes[1] / 2;
  const int N = in_sizes[2];
  const int* src = ei;
  const int* dst = ei + E;
  const int NB = (N + 127) >> BSH;
  const int M  = NB * NBLK;              // phist elements

  char* p = (char*)d_ws;
  bf16_t* t    = (bf16_t*)p;   p += align_up((size_t)N * CDIM * 2);
  bf16_t* h    = (bf16_t*)p;   p += align_up((size_t)N * CDIM * 2);
  int* rowptr  = (int*)p;      p += align_up((size_t)(N + 1) * 4);
  int* colx    = (int*)p;      p += align_up((size_t)E * 4);
  unsigned* tmp= (unsigned*)p; p += align_up((size_t)E * 4);
  float* dinv  = (float*)p;    p += align_up((size_t)N * 4);
  int* phist   = (int*)p;      p += align_up((size_t)M * 4);
  int* btot    = (int*)p;      p += align_up((size_t)NB * 4);
  int* bbase   = (int*)p;      p += align_up((size_t)(NB + 1) * 4);
  bf16_t* Wtg1 = (bf16_t*)p;   p += align_up((size_t)CDIM * CDIM * 2);
  bf16_t* Wtg2 = (bf16_t*)p;   p += align_up((size_t)CDIM * CDIM * 2);
  float* gb    = (float*)p;    p += align_up((size_t)NGRAPH * CDIM * 4);
  (void)ws_size; (void)n_in; (void)out_size;

  k_phist<<<NBLK, 1024, 0, stream>>>(dst, phist, W1, W2, Wtg1, Wtg2, gb, E, NB);
  k_bscan<<<NB, 256, 0, stream>>>(phist, btot);
  k_boff<<<1, 1024, 0, stream>>>(btot, bbase, NB);
  k_pscatter<<<NBLK, 1024, 0, stream>>>(src, dst, phist, bbase, tmp, E, NB);
  k_csort2<<<NB, 256, 0, stream>>>(tmp, bbase, rowptr, dinv, colx, N, NB, E);

  k_gemm<0><<<512, 256, 0, stream>>>(x, Wtg1, t, N);
  k_agg0<<<(N + 3) / 4, 256, 0, stream>>>(t, rowptr, colx, dinv, b1, h, N);
  k_gemm<1><<<512, 256, 0, stream>>>(h, Wtg2, t, N);
  int pwaves = (N + 15) / 16;
  k_aggp<<<(pwaves + 3) / 4, 256, 0, stream>>>(t, rowptr, colx, dinv, b2,
                                               bat, gb, N);
  k_mlp<<<NGRAPH, 512, 0, stream>>>(gb, bat, N, Wm1, bm1, Wm2, bm2, Wm3, bm3, out);
}